// Round 1
// baseline (667.286 us; speedup 1.0000x reference)
//
#include <hip/hip_runtime.h>
#include <hip/hip_bf16.h>
#include <cmath>

// Problem: N=64, T=512, D=256, H=256 (all fp32)
//   c   = x @ Wx + b          (N,T,H)  -- big parallel GEMM (phase 1)
//   h_t = tanh(c_t + h_{t-1} @ Wh)     -- sequential scan   (phase 2)
// Output: all h_t, (N,T,H).
//
// Phase 1 writes c directly into d_out; phase 2 updates d_out in place.
// Phase 2: 64 blocks (one per batch row; sync-free parallelism caps at 64),
// 1024 threads, Wh persistent in VGPRs (64/thread), h in LDS (wave-broadcast
// reads), 4-way K-group partial reduction through LDS.

#define M_TOT 32768   // N*T
#define KDIM  256
#define HDIM  256
#define TSTEPS 512
#define NBATCH 64

// ---------------- Phase 1: c = x @ Wx + b ----------------
// 64x64 tile per block, K-chunks of 64, 256 threads, 4x4 outputs/thread.
__global__ __launch_bounds__(256) void xw_gemm(
    const float* __restrict__ x,    // (32768, 256)
    const float* __restrict__ Wx,   // (256, 256)
    const float* __restrict__ bias, // (256)
    float* __restrict__ out)        // (32768, 256)
{
    __shared__ float As[64][68];   // [row][k]  (+4 pad)
    __shared__ float Bs[64][68];   // [k][col]  (+4 pad)

    const int tid = threadIdx.x;
    const int tx = tid & 15;        // 0..15 -> 4 output cols each
    const int ty = tid >> 4;        // 0..15 -> 4 output rows each
    const int m0 = blockIdx.x * 64;
    const int n0 = blockIdx.y * 64;

    float acc[4][4];
#pragma unroll
    for (int i = 0; i < 4; ++i)
#pragma unroll
        for (int j = 0; j < 4; ++j) acc[i][j] = 0.f;

    for (int kc = 0; kc < KDIM; kc += 64) {
#pragma unroll
        for (int l = 0; l < 4; ++l) {
            int idx = tid + l * 256;          // 0..1023 float4 slots
            int row = idx >> 4;
            int c4  = (idx & 15) << 2;
            float4 va = *(const float4*)&x [(size_t)(m0 + row) * KDIM + kc + c4];
            float4 vb = *(const float4*)&Wx[(size_t)(kc + row) * HDIM + n0 + c4];
            *(float4*)&As[row][c4] = va;
            *(float4*)&Bs[row][c4] = vb;
        }
        __syncthreads();

#pragma unroll
        for (int kk = 0; kk < 64; kk += 4) {
            float4 a[4], bv[4];
#pragma unroll
            for (int i = 0; i < 4; ++i) a[i]  = *(const float4*)&As[ty * 4 + i][kk];
#pragma unroll
            for (int p = 0; p < 4; ++p) bv[p] = *(const float4*)&Bs[kk + p][tx * 4];
#pragma unroll
            for (int i = 0; i < 4; ++i) {
                acc[i][0] += a[i].x * bv[0].x + a[i].y * bv[1].x + a[i].z * bv[2].x + a[i].w * bv[3].x;
                acc[i][1] += a[i].x * bv[0].y + a[i].y * bv[1].y + a[i].z * bv[2].y + a[i].w * bv[3].y;
                acc[i][2] += a[i].x * bv[0].z + a[i].y * bv[1].z + a[i].z * bv[2].z + a[i].w * bv[3].z;
                acc[i][3] += a[i].x * bv[0].w + a[i].y * bv[1].w + a[i].z * bv[2].w + a[i].w * bv[3].w;
            }
        }
        __syncthreads();
    }

    float4 bj = *(const float4*)&bias[n0 + tx * 4];
#pragma unroll
    for (int i = 0; i < 4; ++i) {
        float4 v;
        v.x = acc[i][0] + bj.x;
        v.y = acc[i][1] + bj.y;
        v.z = acc[i][2] + bj.z;
        v.w = acc[i][3] + bj.w;
        *(float4*)&out[(size_t)(m0 + ty * 4 + i) * HDIM + n0 + tx * 4] = v;
    }
}

// ---------------- Phase 2: sequential scan ----------------
// One block per batch row. 1024 threads: j = column (0..255), g = K-group
// (0..3, 64 k's each). Wh[64g:64g+64, j] persistent in 64 VGPRs.
__global__ __launch_bounds__(1024) void rnn_scan(
    const float* __restrict__ h0,   // (64, 256)
    const float* __restrict__ Wh,   // (256, 256)
    float* __restrict__ out)        // (64, 512, 256), holds c; overwritten with h
{
    const int r  = blockIdx.x;      // batch row
    const int tid = threadIdx.x;
    const int j = tid & 255;
    const int g = tid >> 8;

    __shared__ float h[256];
    __shared__ float red[4][256];

    // Load this thread's Wh column slice into registers (coalesced per i).
    float W[64];
    const float* wp = Wh + (size_t)(g * 64) * HDIM + j;
#pragma unroll
    for (int i = 0; i < 64; ++i) W[i] = wp[(size_t)i * HDIM];

    if (tid < 256) h[tid] = h0[(size_t)r * HDIM + tid];

    float* outr = out + (size_t)r * TSTEPS * HDIM;
    __syncthreads();

    for (int t = 0; t < TSTEPS; ++t) {
        // Prefetch c_t (phase-1 result) -- latency hidden behind the FMA phase.
        float c = 0.f;
        if (tid < 256) c = outr[(size_t)t * HDIM + j];

        // FMA phase: partial_j^g = sum_{i<64} h[64g+i] * Wh[64g+i][j]
        // All lanes of a wave read the same LDS address -> broadcast (free).
        float a0 = 0.f, a1 = 0.f, a2 = 0.f, a3 = 0.f;
        const float4* hv = (const float4*)(h + (g << 6));
#pragma unroll
        for (int i = 0; i < 16; ++i) {
            float4 hh = hv[i];
            a0 += hh.x * W[4 * i + 0];
            a1 += hh.y * W[4 * i + 1];
            a2 += hh.z * W[4 * i + 2];
            a3 += hh.w * W[4 * i + 3];
        }
        red[g][j] = (a0 + a1) + (a2 + a3);
        __syncthreads();

        if (tid < 256) {
            float s = ((red[0][j] + red[1][j]) + (red[2][j] + red[3][j])) + c;
            float hn = tanhf(s);
            outr[(size_t)t * HDIM + j] = hn;   // in-place: c was read above
            h[j] = hn;                         // safe: all FMA reads done (barrier)
        }
        __syncthreads();   // next step's FMA must see updated h
    }
}

extern "C" void kernel_launch(void* const* d_in, const int* in_sizes, int n_in,
                              void* d_out, int out_size, void* d_ws, size_t ws_size,
                              hipStream_t stream) {
    const float* x  = (const float*)d_in[0];   // (64,512,256)
    const float* h0 = (const float*)d_in[1];   // (64,256)
    const float* Wx = (const float*)d_in[2];   // (256,256)
    const float* Wh = (const float*)d_in[3];   // (256,256)
    const float* b  = (const float*)d_in[4];   // (256)
    float* out = (float*)d_out;                // (64,512,256)

    // Phase 1: input projection into d_out.
    dim3 g1(M_TOT / 64, HDIM / 64);
    xw_gemm<<<g1, 256, 0, stream>>>(x, Wx, b, out);

    // Phase 2: sequential scan, in place.
    rnn_scan<<<NBATCH, 1024, 0, stream>>>(h0, Wh, out);
}